// Round 2
// baseline (234.505 us; speedup 1.0000x reference)
//
#include <hip/hip_runtime.h>

#define NXg 4096
#define NYg 4096
#define TR 32              // core rows per tile
#define TC 256             // core cols per tile
#define ER (TR + 4)        // 36 extended rows  (core +/- 2)
#define EC (TC + 4)        // 260 extended cols (core +/- 2)

// CX = Z*DT/DX = (1/400) * 4095 = 10.2375 ; DX == DY so CY == CX.
static constexpr float CX = 10.2375f;
static constexpr float CY = 10.2375f;

__device__ __forceinline__ float ld_guard(const float* __restrict__ p,
                                          int r, int c, bool cok) {
    return (cok && r >= 0 && r < NXg) ? p[r * NYg + c] : 0.0f;
}

// ---------------------------------------------------------------------------
// Fused kernel: phase 1 computes final E on the extended tile into LDS
// (recomputing the 2-wide halo); phase 2 computes Hx/Hy from LDS-resident E
// and writes all three outputs. X stencil re-reads are absorbed by L1/L2.
// ---------------------------------------------------------------------------
__global__ __launch_bounds__(256) void fused_kernel(
    const float* __restrict__ X1, const float* __restrict__ X2,
    const float* __restrict__ X3, const float* __restrict__ w1,
    float* __restrict__ E, float* __restrict__ Hx, float* __restrict__ Hy)
{
    __shared__ float elds[ER][EC];

    const int t    = threadIdx.x;          // 0..255
    const int row0 = blockIdx.y * TR;      // core row base
    const int col0 = blockIdx.x * TC;      // core col base

    const float w  = w1[0];
    const float f0 = (w - 1.0f) / 3.0f;
    const float f1 = -w;
    const float f2 = w;
    const float f3 = (1.0f - w) / 3.0f;

    // ---------------- Phase 1: E on extended tile ----------------
    {
        const int  gc  = col0 + t - 2;                 // ext col cc = t
        const bool cok = (gc >= 0) && (gc < NYg);

        // rolling X3 window: rows gr-2, gr-1, gr, gr+1 for current ext row gr
        float x3a = ld_guard(X3, row0 - 4, gc, cok);
        float x3b = ld_guard(X3, row0 - 3, gc, cok);
        float x3c = ld_guard(X3, row0 - 2, gc, cok);
        float x3d = ld_guard(X3, row0 - 1, gc, cok);

        for (int r = 0; r < ER; ++r) {
            const int gr = row0 + r - 2;

            float e = 0.0f;
            if (cok && gr >= 0 && gr < NXg) {
                const float x1 = X1[gr * NYg + gc];
                if (gr == 0 || gr == NXg - 1 || gc == 0 || gc == NYg - 1) {
                    e = x1;  // untouched boundary ring
                } else {
                    const float x2m1 = X2[gr * NYg + gc - 1];
                    const float x2p0 = X2[gr * NYg + gc];
                    const float e1 = x1 + CX * (x3c - x3b)
                                        - CY * (x2p0 - x2m1);
                    e = e1;
                    if (gr >= 2 && gr <= NXg - 3 && gc >= 2 && gc <= NYg - 3) {
                        const float x2m2 = X2[gr * NYg + gc - 2];
                        const float x2p1 = X2[gr * NYg + gc + 1];
                        const float s1 = f0 * x3a + f1 * x3b + f2 * x3c + f3 * x3d;
                        const float s2 = f0 * x2m2 + f1 * x2m1 + f2 * x2p0 + f3 * x2p1;
                        e = e1 + CX * s1 - CY * s2;
                    }
                }
            }
            elds[r][t] = e;

            // extra ext cols cc = 256..259 handled by threads 0..3
            if (t < 4) {
                const int  cc2  = TC + t;             // 256..259
                const int  gc2  = col0 + cc2 - 2;     // >= 254
                const bool cok2 = (gc2 < NYg);
                float e2 = 0.0f;
                if (cok2 && gr >= 0 && gr < NXg) {
                    const float x1 = X1[gr * NYg + gc2];
                    if (gr == 0 || gr == NXg - 1 || gc2 == 0 || gc2 == NYg - 1) {
                        e2 = x1;
                    } else {
                        const float y3b  = X3[(gr - 1) * NYg + gc2];
                        const float y3c  = X3[gr * NYg + gc2];
                        const float x2m1 = X2[gr * NYg + gc2 - 1];
                        const float x2p0 = X2[gr * NYg + gc2];
                        const float e1 = x1 + CX * (y3c - y3b)
                                            - CY * (x2p0 - x2m1);
                        e2 = e1;
                        if (gr >= 2 && gr <= NXg - 3 &&
                            gc2 >= 2 && gc2 <= NYg - 3) {
                            const float y3a  = X3[(gr - 2) * NYg + gc2];
                            const float y3d  = X3[(gr + 1) * NYg + gc2];
                            const float x2m2 = X2[gr * NYg + gc2 - 2];
                            const float x2p1 = X2[gr * NYg + gc2 + 1];
                            const float s1 = f0 * y3a + f1 * y3b + f2 * y3c + f3 * y3d;
                            const float s2 = f0 * x2m2 + f1 * x2m1 + f2 * x2p0 + f3 * x2p1;
                            e2 = e1 + CX * s1 - CY * s2;
                        }
                    }
                }
                elds[r][cc2] = e2;
            }

            // roll: next iteration (gr+1) needs X3 rows gr-1 .. gr+2
            x3a = x3b; x3b = x3c; x3c = x3d;
            x3d = ld_guard(X3, row0 + r, gc, cok);
        }
    }

    __syncthreads();

    // ---------------- Phase 2: Hx, Hy (+ E store) on core tile ----------------
    {
        const int gcc = col0 + t;   // core col
        for (int hr = 0; hr < TR; ++hr) {
            const int gr  = row0 + hr;
            const int idx = gr * NYg + gcc;

            const float ec = elds[hr + 2][t + 2];
            E[idx] = ec;

            const float x1 = X1[idx];

            // ---- Hx ----
            float hx = X2[idx];
            if (gr >= 1 && gr <= NXg - 2 && gcc <= NYg - 2)
                hx -= CY * (X1[idx + 1] - x1);
            if (gr >= 2 && gr <= NXg - 3 && gcc >= 1 && gcc <= NYg - 3) {
                const float s3 = f0 * elds[hr + 2][t + 1] + f1 * ec
                               + f2 * elds[hr + 2][t + 3] + f3 * elds[hr + 2][t + 4];
                hx -= CY * s3;
            }
            Hx[idx] = hx;

            // ---- Hy ----
            float hy = X3[idx];
            if (gr <= NXg - 2 && gcc >= 1 && gcc <= NYg - 2)
                hy += CX * (X1[idx + NYg] - x1);
            if (gr >= 1 && gr <= NXg - 3 && gcc >= 2 && gcc <= NYg - 3) {
                const float s4 = f0 * elds[hr + 1][t + 2] + f1 * ec
                               + f2 * elds[hr + 3][t + 2] + f3 * elds[hr + 4][t + 2];
                hy += CX * s4;
            }
            Hy[idx] = hy;
        }
    }
}

extern "C" void kernel_launch(void* const* d_in, const int* in_sizes, int n_in,
                              void* d_out, int out_size, void* d_ws, size_t ws_size,
                              hipStream_t stream) {
    const float* X1 = (const float*)d_in[0];
    const float* X2 = (const float*)d_in[1];
    const float* X3 = (const float*)d_in[2];
    const float* w1 = (const float*)d_in[3];

    float* E  = (float*)d_out;
    float* Hx = (float*)d_out + (size_t)NXg * NYg;
    float* Hy = (float*)d_out + 2 * (size_t)NXg * NYg;

    dim3 block(256);
    dim3 grid(NYg / TC, NXg / TR);   // (16, 128)
    fused_kernel<<<grid, block, 0, stream>>>(X1, X2, X3, w1, E, Hx, Hy);
}

// Round 3
// 141.887 us; speedup vs baseline: 1.6528x; 1.6528x over previous
//
#include <hip/hip_runtime.h>

#define NXg 4096
#define NYg 4096
#define TR 32               // core rows per tile
#define TC 128              // core cols per tile
#define EROWS 36            // ext rows: row0-2 .. row0+33
#define ECOLS 136           // ext cols: col0-4 .. col0+131 (padded to float4 align)
#define EGRP  34            // ECOLS / 4

// CX = Z*DT/DX = (1/400) * 4095 = 10.2375 ; DX == DY so CY == CX.
static constexpr float CX = 10.2375f;
static constexpr float CY = 10.2375f;

__global__ __launch_bounds__(256) void fused_kernel(
    const float* __restrict__ X1, const float* __restrict__ X2,
    const float* __restrict__ X3, const float* __restrict__ w1,
    float* __restrict__ E, float* __restrict__ Hx, float* __restrict__ Hy)
{
    __shared__ float elds[EROWS][ECOLS];

    const int t    = threadIdx.x;          // 0..255
    const int row0 = blockIdx.y * TR;
    const int col0 = blockIdx.x * TC;

    const float w  = w1[0];
    const float f0 = (w - 1.0f) / 3.0f;
    const float f1 = -w;
    const float f2 = w;
    const float f3 = (1.0f - w) / 3.0f;

    // interior block: every ext cell is within [2, 4093]^2 (full f4 path, no ring)
    const bool interior =
        (blockIdx.y >= 1) && (blockIdx.y <= (NXg / TR) - 2) &&
        (blockIdx.x >= 1) && (blockIdx.x <= (NYg / TC) - 2);

    if (interior) {
        // ---------------- Phase 1 (fast): E on ext tile, float4 ----------------
        for (int c = t; c < EROWS * EGRP; c += 256) {
            const int r  = c / EGRP;
            const int g  = c - r * EGRP;
            const int gr = row0 - 2 + r;
            const int gc = col0 - 4 + g * 4;
            const size_t off = (size_t)gr * NYg + gc;

            const float4 x1v = *(const float4*)(X1 + off);
            const float4 a2  = *(const float4*)(X2 + off - 4);
            const float4 b2  = *(const float4*)(X2 + off);
            const float  c2  = X2[off + 4];
            const float4 x3a = *(const float4*)(X3 + off - 2 * NYg);
            const float4 x3b = *(const float4*)(X3 + off - NYg);
            const float4 x3c = *(const float4*)(X3 + off);
            const float4 x3d = *(const float4*)(X3 + off + NYg);

            const float W[7]  = {a2.z, a2.w, b2.x, b2.y, b2.z, b2.w, c2};  // X2[gc-2+k]
            const float V1[4] = {x1v.x, x1v.y, x1v.z, x1v.w};
            const float A3[4] = {x3a.x, x3a.y, x3a.z, x3a.w};
            const float B3[4] = {x3b.x, x3b.y, x3b.z, x3b.w};
            const float C3[4] = {x3c.x, x3c.y, x3c.z, x3c.w};
            const float D3[4] = {x3d.x, x3d.y, x3d.z, x3d.w};

            float out[4];
            #pragma unroll
            for (int m = 0; m < 4; ++m) {
                const float e1 = V1[m] + CX * (C3[m] - B3[m])
                                       - CY * (W[m + 2] - W[m + 1]);
                out[m] = e1
                    + CX * (f0 * A3[m] + f1 * B3[m] + f2 * C3[m] + f3 * D3[m])
                    - CY * (f0 * W[m] + f1 * W[m + 1] + f2 * W[m + 2] + f3 * W[m + 3]);
            }
            *(float4*)&elds[r][g * 4] = make_float4(out[0], out[1], out[2], out[3]);
        }

        __syncthreads();

        // ---------------- Phase 2 (fast): Hx, Hy, E store, float4 ----------------
        const int tx = t & 31;
        const int ty = t >> 5;
        const int lc = 4 + tx * 4;          // ext col offset of this thread's group

        #pragma unroll
        for (int k = 0; k < 4; ++k) {
            const int hr = ty + 8 * k;      // core row 0..31
            const int gr = row0 + hr;
            const int gc = col0 + tx * 4;
            const size_t idx = (size_t)gr * NYg + gc;
            const int lr = hr + 2;

            const float4 em1 = *(const float4*)&elds[lr - 1][lc];
            const float4 e0  = *(const float4*)&elds[lr][lc];
            const float4 ep1 = *(const float4*)&elds[lr + 1][lc];
            const float4 ep2 = *(const float4*)&elds[lr + 2][lc];
            const float  eL  = elds[lr][lc - 1];
            const float  eR4 = elds[lr][lc + 4];
            const float  eR5 = elds[lr][lc + 5];

            const float4 x1v = *(const float4*)(X1 + idx);
            const float  x1r = X1[idx + 4];
            const float4 x1d = *(const float4*)(X1 + idx + NYg);
            const float4 x2v = *(const float4*)(X2 + idx);
            const float4 x3v = *(const float4*)(X3 + idx);

            *(float4*)(E + idx) = e0;

            const float EW[7]  = {eL, e0.x, e0.y, e0.z, e0.w, eR4, eR5};  // E[i][gc-1+k]
            const float V1[4]  = {x1v.x, x1v.y, x1v.z, x1v.w};
            const float V1n[4] = {x1v.y, x1v.z, x1v.w, x1r};              // X1[i][j+1]
            const float D1[4]  = {x1d.x, x1d.y, x1d.z, x1d.w};            // X1[i+1][j]
            const float V2[4]  = {x2v.x, x2v.y, x2v.z, x2v.w};
            const float V3[4]  = {x3v.x, x3v.y, x3v.z, x3v.w};
            const float M1[4]  = {em1.x, em1.y, em1.z, em1.w};
            const float E0[4]  = {e0.x, e0.y, e0.z, e0.w};
            const float P1[4]  = {ep1.x, ep1.y, ep1.z, ep1.w};
            const float P2[4]  = {ep2.x, ep2.y, ep2.z, ep2.w};

            float hx[4], hy[4];
            #pragma unroll
            for (int m = 0; m < 4; ++m) {
                hx[m] = V2[m] - CY * (V1n[m] - V1[m])
                      - CY * (f0 * EW[m] + f1 * EW[m + 1]
                            + f2 * EW[m + 2] + f3 * EW[m + 3]);
                hy[m] = V3[m] + CX * (D1[m] - V1[m])
                      + CX * (f0 * M1[m] + f1 * E0[m] + f2 * P1[m] + f3 * P2[m]);
            }
            *(float4*)(Hx + idx) = make_float4(hx[0], hx[1], hx[2], hx[3]);
            *(float4*)(Hy + idx) = make_float4(hy[0], hy[1], hy[2], hy[3]);
        }
        return;
    }

    // ======================= boundary blocks (slow path) =======================
    // ---------------- Phase 1: scalar, fully guarded ----------------
    for (int c = t; c < EROWS * ECOLS; c += 256) {
        const int r  = c / ECOLS;
        const int cc = c - r * ECOLS;
        const int gr = row0 - 2 + r;
        const int gc = col0 - 4 + cc;

        float e = 0.0f;
        if (gr >= 0 && gr < NXg && gc >= 0 && gc < NYg) {
            const size_t idx = (size_t)gr * NYg + gc;
            const float x1 = X1[idx];
            if (gr == 0 || gr == NXg - 1 || gc == 0 || gc == NYg - 1) {
                e = x1;
            } else {
                float e1 = x1 + CX * (X3[idx] - X3[idx - NYg])
                              - CY * (X2[idx] - X2[idx - 1]);
                if (gr >= 2 && gr <= NXg - 3 && gc >= 2 && gc <= NYg - 3) {
                    e1 += CX * (f0 * X3[idx - 2 * NYg] + f1 * X3[idx - NYg]
                              + f2 * X3[idx] + f3 * X3[idx + NYg])
                        - CY * (f0 * X2[idx - 2] + f1 * X2[idx - 1]
                              + f2 * X2[idx] + f3 * X2[idx + 1]);
                }
                e = e1;
            }
        }
        elds[r][cc] = e;
    }

    __syncthreads();

    // ---------------- Phase 2: scalar, fully guarded ----------------
    for (int c = t; c < TR * TC; c += 256) {
        const int hr  = c >> 7;
        const int tc  = c & (TC - 1);
        const int gr  = row0 + hr;
        const int gcc = col0 + tc;
        const size_t idx = (size_t)gr * NYg + gcc;
        const int lr  = hr + 2;
        const int lc2 = tc + 4;

        const float ec = elds[lr][lc2];
        E[idx] = ec;

        const float x1 = X1[idx];

        float hx = X2[idx];
        if (gr >= 1 && gr <= NXg - 2 && gcc <= NYg - 2)
            hx -= CY * (X1[idx + 1] - x1);
        if (gr >= 2 && gr <= NXg - 3 && gcc >= 1 && gcc <= NYg - 3) {
            const float s3 = f0 * elds[lr][lc2 - 1] + f1 * ec
                           + f2 * elds[lr][lc2 + 1] + f3 * elds[lr][lc2 + 2];
            hx -= CY * s3;
        }
        Hx[idx] = hx;

        float hy = X3[idx];
        if (gr <= NXg - 2 && gcc >= 1 && gcc <= NYg - 2)
            hy += CX * (X1[idx + NYg] - x1);
        if (gr >= 1 && gr <= NXg - 3 && gcc >= 2 && gcc <= NYg - 3) {
            const float s4 = f0 * elds[lr - 1][lc2] + f1 * ec
                           + f2 * elds[lr + 1][lc2] + f3 * elds[lr + 2][lc2];
            hy += CX * s4;
        }
        Hy[idx] = hy;
    }
}

extern "C" void kernel_launch(void* const* d_in, const int* in_sizes, int n_in,
                              void* d_out, int out_size, void* d_ws, size_t ws_size,
                              hipStream_t stream) {
    const float* X1 = (const float*)d_in[0];
    const float* X2 = (const float*)d_in[1];
    const float* X3 = (const float*)d_in[2];
    const float* w1 = (const float*)d_in[3];

    float* E  = (float*)d_out;
    float* Hx = (float*)d_out + (size_t)NXg * NYg;
    float* Hy = (float*)d_out + 2 * (size_t)NXg * NYg;

    dim3 block(256);
    dim3 grid(NYg / TC, NXg / TR);   // (32, 128)
    fused_kernel<<<grid, block, 0, stream>>>(X1, X2, X3, w1, E, Hx, Hy);
}

// Round 4
// 115.751 us; speedup vs baseline: 2.0259x; 1.2258x over previous
//
#include <hip/hip_runtime.h>

#define NXg 4096
#define NYg 4096
#define RPT 16                 // output rows per thread (fat kernel)
#define ROW0 8                 // fat kernel covers rows [8, 4087]
#define NBANDS 255             // (4088-8)/16

static constexpr float C = 10.2375f;   // Z*DT/DX = (1/400)*4095 ; DX==DY

struct F7  { float v[7];  };   // cols c0-1 .. c0+5
struct F10 { float v[10]; };   // cols c0-3 .. c0+6

// Load 12 consecutive floats at row r, cols c0-4 .. c0+7 (three aligned float4).
// In-bounds for all uses: r in [5, 4091] -> o-4 >= 0, o+4+3 < 4096^2.
// At col edges the outer float4s contain neighboring-row data; consumed only by
// lanes whose results are overridden by gL/gR fixups.
__device__ __forceinline__ void ld12(const float* __restrict__ P, int r, int c0,
                                     float4& a, float4& b, float4& c) {
    const size_t o = (size_t)r * NYg + c0;
    a = *(const float4*)(P + o - 4);
    b = *(const float4*)(P + o);
    c = *(const float4*)(P + o + 4);
}

__device__ __forceinline__ F7 mk7(const float4& a, const float4& b, const float4& c) {
    F7 r;
    r.v[0] = a.w; r.v[1] = b.x; r.v[2] = b.y; r.v[3] = b.z;
    r.v[4] = b.w; r.v[5] = c.x; r.v[6] = c.y;
    return r;
}
__device__ __forceinline__ F10 mk10(const float4& a, const float4& b, const float4& c) {
    F10 r;
    r.v[0] = a.y; r.v[1] = a.z; r.v[2] = a.w;
    r.v[3] = b.x; r.v[4] = b.y; r.v[5] = b.z; r.v[6] = b.w;
    r.v[7] = c.x; r.v[8] = c.y; r.v[9] = c.z;
    return r;
}

__device__ __forceinline__ F7 ld7(const float* __restrict__ P, int r, int c0) {
    float4 a, b, c; ld12(P, r, c0, a, b, c); return mk7(a, b, c);
}
__device__ __forceinline__ F10 ld10(const float* __restrict__ P, int r, int c0) {
    float4 a, b, c; ld12(P, r, c0, a, b, c); return mk10(a, b, c);
}

// ---------------------------------------------------------------------------
// Fat kernel: rows [8, 4087], all cols. Each thread owns cols c0..c0+3 and
// walks RPT rows with rolling register windows; E is computed 7-wide
// (cols c0-1..c0+5) so Hx/Hy need no cross-thread exchange. No LDS, no barrier.
// ---------------------------------------------------------------------------
__global__ __launch_bounds__(256, 3) void fat_kernel(
    const float* __restrict__ X1, const float* __restrict__ X2,
    const float* __restrict__ X3, const float* __restrict__ w1,
    float* __restrict__ E, float* __restrict__ Hx, float* __restrict__ Hy)
{
    const int t  = threadIdx.x;
    const int c0 = (blockIdx.x * 256 + t) * 4;
    const int i0 = ROW0 + blockIdx.y * RPT;
    const bool gL = (c0 == 0);
    const bool gR = (c0 == NYg - 4);

    const float wv = w1[0];
    const float f0 = (wv - 1.0f) / 3.0f;
    const float f1 = -wv;
    const float f2 = wv;
    const float f3 = (1.0f - wv) / 3.0f;

    // E row r (7-wide): taps X3[r-2..r+1], X2[r] (10-wide), X1[r] (7-wide).
    // All rows here are in [2,4093] so only column fixups are needed.
    auto eRow = [&](const F7& x3m2, const F7& x3m1, const F7& x3p0, const F7& x3p1,
                    const F10& x2r, const F7& x1r) -> F7 {
        F7 e;
        #pragma unroll
        for (int m = 0; m < 7; ++m) {
            const float e1 = x1r.v[m] + C * (x3p0.v[m] - x3m1.v[m])
                                      - C * (x2r.v[m + 2] - x2r.v[m + 1]);
            e.v[m] = e1
                + C * (f0 * x3m2.v[m] + f1 * x3m1.v[m] + f2 * x3p0.v[m] + f3 * x3p1.v[m])
                - C * (f0 * x2r.v[m] + f1 * x2r.v[m + 1] + f2 * x2r.v[m + 2] + f3 * x2r.v[m + 3]);
        }
        if (gL) {
            // m=1 -> j=0 : boundary copy ; m=2 -> j=1 : BC step only
            e.v[1] = x1r.v[1];
            e.v[2] = x1r.v[2] + C * (x3p0.v[2] - x3m1.v[2])
                              - C * (x2r.v[4] - x2r.v[3]);
        }
        if (gR) {
            // m=4 -> j=4095 : boundary copy ; m=3 -> j=4094 : BC step only
            e.v[4] = x1r.v[4];
            e.v[3] = x1r.v[3] + C * (x3p0.v[3] - x3m1.v[3])
                              - C * (x2r.v[5] - x2r.v[4]);
        }
        return e;
    };

    // ---------------- Prologue: fill windows for i = i0 ----------------
    F7 p3a = ld7(X3, i0 - 3, c0);
    F7 p3b = ld7(X3, i0 - 2, c0);
    F7 p3c = ld7(X3, i0 - 1, c0);
    F7 w3[4];
    w3[0] = ld7(X3, i0,     c0);
    w3[1] = ld7(X3, i0 + 1, c0);
    w3[2] = ld7(X3, i0 + 2, c0);
    w3[3] = ld7(X3, i0 + 3, c0);

    F10 q2a = ld10(X2, i0 - 1, c0);
    F10 q2b = ld10(X2, i0,     c0);
    F10 q2c = ld10(X2, i0 + 1, c0);
    F10 w2r = ld10(X2, i0 + 2, c0);   // X2 row i+2

    F7 q1a = ld7(X1, i0 - 1, c0);
    F7 w1r[3];
    w1r[0] = ld7(X1, i0,     c0);
    w1r[1] = ld7(X1, i0 + 1, c0);
    w1r[2] = ld7(X1, i0 + 2, c0);

    F7 ew[4];                          // E rows i-1 .. i+2
    ew[0] = eRow(p3a, p3b, p3c, w3[0], q2a, q1a);      // E[i0-1]
    ew[1] = eRow(p3b, p3c, w3[0], w3[1], q2b, w1r[0]); // E[i0]
    ew[2] = eRow(p3c, w3[0], w3[1], w3[2], q2c, w1r[1]); // E[i0+1]

    float x2c0[4] = {q2b.v[3], q2b.v[4], q2b.v[5], q2b.v[6]};  // X2[i] centers
    float x2c1[4] = {q2c.v[3], q2c.v[4], q2c.v[5], q2c.v[6]};  // X2[i+1] centers

    // ---------------- Main loop over output rows ----------------
    #pragma unroll
    for (int s = 0; s < RPT; ++s) {
        const int i = i0 + s;

        // issue next-step loads early (consumed next iteration)
        F7  t3; F10 t2; F7 t1;
        if (s < RPT - 1) {
            t3 = ld7(X3, i + 4, c0);
            t2 = ld10(X2, i + 3, c0);
            t1 = ld7(X1, i + 3, c0);
        }

        // E row i+2 from already-resident windows
        ew[3] = eRow(w3[0], w3[1], w3[2], w3[3], w2r, w1r[2]);

        // ---- outputs for row i ----
        float hx[4], hy[4];
        #pragma unroll
        for (int q = 0; q < 4; ++q) {
            hx[q] = x2c0[q] - C * (w1r[0].v[q + 2] - w1r[0].v[q + 1])
                  - C * (f0 * ew[1].v[q]     + f1 * ew[1].v[q + 1]
                       + f2 * ew[1].v[q + 2] + f3 * ew[1].v[q + 3]);
            hy[q] = w3[0].v[q + 1] + C * (w1r[1].v[q + 1] - w1r[0].v[q + 1])
                  + C * (f0 * ew[0].v[q + 1] + f1 * ew[1].v[q + 1]
                       + f2 * ew[2].v[q + 1] + f3 * ew[3].v[q + 1]);
        }
        if (gL) {
            hx[0] = x2c0[0] - C * (w1r[0].v[2] - w1r[0].v[1]);   // j=0: no f4
            hy[0] = w3[0].v[1];                                  // j=0: copy X3
            hy[1] = w3[0].v[2] + C * (w1r[1].v[2] - w1r[0].v[2]); // j=1: no f4
        }
        if (gR) {
            hx[3] = x2c0[3];                                     // j=4095: copy X2
            hy[3] = w3[0].v[4];                                  // j=4095: copy X3
            hx[2] = x2c0[2] - C * (w1r[0].v[4] - w1r[0].v[3]);   // j=4094: no f4
            hy[2] = w3[0].v[3] + C * (w1r[1].v[3] - w1r[0].v[3]); // j=4094: no f4
        }

        const size_t idx = (size_t)i * NYg + c0;
        *(float4*)(E  + idx) = make_float4(ew[1].v[1], ew[1].v[2], ew[1].v[3], ew[1].v[4]);
        *(float4*)(Hx + idx) = make_float4(hx[0], hx[1], hx[2], hx[3]);
        *(float4*)(Hy + idx) = make_float4(hy[0], hy[1], hy[2], hy[3]);

        // ---- roll windows ----
        ew[0] = ew[1]; ew[1] = ew[2]; ew[2] = ew[3];
        w3[0] = w3[1]; w3[1] = w3[2]; w3[2] = w3[3];
        w1r[0] = w1r[1]; w1r[1] = w1r[2];
        #pragma unroll
        for (int q = 0; q < 4; ++q) { x2c0[q] = x2c1[q]; x2c1[q] = w2r.v[3 + q]; }
        if (s < RPT - 1) { w3[3] = t3; w2r = t2; w1r[2] = t1; }
    }
}

// ---------------------------------------------------------------------------
// Edge kernel: boundary row bands [0,7] and [4088,4095], fully guarded
// (round-3 proven slow path with an 8-row tile).
// ---------------------------------------------------------------------------
#define TRE 8
#define EROWSE 12
#define ECOLSE 136

__global__ __launch_bounds__(256) void edge_kernel(
    const float* __restrict__ X1, const float* __restrict__ X2,
    const float* __restrict__ X3, const float* __restrict__ w1,
    float* __restrict__ E, float* __restrict__ Hx, float* __restrict__ Hy)
{
    __shared__ float elds[EROWSE][ECOLSE];
    const int t    = threadIdx.x;
    const int row0 = blockIdx.y ? (NXg - TRE) : 0;
    const int col0 = blockIdx.x * 128;

    const float wv = w1[0];
    const float f0 = (wv - 1.0f) / 3.0f;
    const float f1 = -wv;
    const float f2 = wv;
    const float f3 = (1.0f - wv) / 3.0f;

    for (int cidx = t; cidx < EROWSE * ECOLSE; cidx += 256) {
        const int r  = cidx / ECOLSE;
        const int cc = cidx - r * ECOLSE;
        const int gr = row0 - 2 + r;
        const int gc = col0 - 4 + cc;
        float e = 0.0f;
        if (gr >= 0 && gr < NXg && gc >= 0 && gc < NYg) {
            const size_t idx = (size_t)gr * NYg + gc;
            const float x1 = X1[idx];
            if (gr == 0 || gr == NXg - 1 || gc == 0 || gc == NYg - 1) {
                e = x1;
            } else {
                float e1 = x1 + C * (X3[idx] - X3[idx - NYg])
                              - C * (X2[idx] - X2[idx - 1]);
                if (gr >= 2 && gr <= NXg - 3 && gc >= 2 && gc <= NYg - 3) {
                    e1 += C * (f0 * X3[idx - 2 * NYg] + f1 * X3[idx - NYg]
                             + f2 * X3[idx] + f3 * X3[idx + NYg])
                        - C * (f0 * X2[idx - 2] + f1 * X2[idx - 1]
                             + f2 * X2[idx] + f3 * X2[idx + 1]);
                }
                e = e1;
            }
        }
        elds[r][cc] = e;
    }
    __syncthreads();

    for (int cidx = t; cidx < TRE * 128; cidx += 256) {
        const int hr  = cidx >> 7;
        const int tc  = cidx & 127;
        const int gr  = row0 + hr;
        const int gcc = col0 + tc;
        const size_t idx = (size_t)gr * NYg + gcc;
        const int lr  = hr + 2;
        const int lc2 = tc + 4;

        const float ec = elds[lr][lc2];
        E[idx] = ec;

        const float x1 = X1[idx];

        float hx = X2[idx];
        if (gr >= 1 && gr <= NXg - 2 && gcc <= NYg - 2)
            hx -= C * (X1[idx + 1] - x1);
        if (gr >= 2 && gr <= NXg - 3 && gcc >= 1 && gcc <= NYg - 3) {
            hx -= C * (f0 * elds[lr][lc2 - 1] + f1 * ec
                     + f2 * elds[lr][lc2 + 1] + f3 * elds[lr][lc2 + 2]);
        }
        Hx[idx] = hx;

        float hy = X3[idx];
        if (gr <= NXg - 2 && gcc >= 1 && gcc <= NYg - 2)
            hy += C * (X1[idx + NYg] - x1);
        if (gr >= 1 && gr <= NXg - 3 && gcc >= 2 && gcc <= NYg - 3) {
            hy += C * (f0 * elds[lr - 1][lc2] + f1 * ec
                     + f2 * elds[lr + 1][lc2] + f3 * elds[lr + 2][lc2]);
        }
        Hy[idx] = hy;
    }
}

extern "C" void kernel_launch(void* const* d_in, const int* in_sizes, int n_in,
                              void* d_out, int out_size, void* d_ws, size_t ws_size,
                              hipStream_t stream) {
    const float* X1 = (const float*)d_in[0];
    const float* X2 = (const float*)d_in[1];
    const float* X3 = (const float*)d_in[2];
    const float* w1 = (const float*)d_in[3];

    float* E  = (float*)d_out;
    float* Hx = (float*)d_out + (size_t)NXg * NYg;
    float* Hy = (float*)d_out + 2 * (size_t)NXg * NYg;

    edge_kernel<<<dim3(32, 2),     256, 0, stream>>>(X1, X2, X3, w1, E, Hx, Hy);
    fat_kernel <<<dim3(4, NBANDS), 256, 0, stream>>>(X1, X2, X3, w1, E, Hx, Hy);
}

// Round 5
// 111.719 us; speedup vs baseline: 2.0991x; 1.0361x over previous
//
#include <hip/hip_runtime.h>

#define NXg 4096
#define NYg 4096
#define RPT 8                  // output rows per thread (fat kernel)
#define ROW0 8                 // fat kernel covers rows [8, 4087]
#define NBANDS 510             // (4088-8)/RPT
#define BTHREADS 128           // threads per block (2 waves); block covers 512 cols

static constexpr float C = 10.2375f;   // Z*DT/DX = (1/400)*4095 ; DX==DY

struct F7  { float v[7];  };   // cols c0-1 .. c0+5
struct F10 { float v[10]; };   // cols c0-3 .. c0+6

// Load 12 consecutive floats at row r, cols c0-4 .. c0+7 (three aligned float4).
// In-bounds for all uses: r in [5, 4091] -> o-4 >= 0, o+4+3 < 4096^2.
// At col edges the outer float4s contain neighboring-row data; consumed only by
// lanes whose results are overridden by gL/gR fixups.
__device__ __forceinline__ void ld12(const float* __restrict__ P, int r, int c0,
                                     float4& a, float4& b, float4& c) {
    const size_t o = (size_t)r * NYg + c0;
    a = *(const float4*)(P + o - 4);
    b = *(const float4*)(P + o);
    c = *(const float4*)(P + o + 4);
}

__device__ __forceinline__ F7 mk7(const float4& a, const float4& b, const float4& c) {
    F7 r;
    r.v[0] = a.w; r.v[1] = b.x; r.v[2] = b.y; r.v[3] = b.z;
    r.v[4] = b.w; r.v[5] = c.x; r.v[6] = c.y;
    return r;
}
__device__ __forceinline__ F10 mk10(const float4& a, const float4& b, const float4& c) {
    F10 r;
    r.v[0] = a.y; r.v[1] = a.z; r.v[2] = a.w;
    r.v[3] = b.x; r.v[4] = b.y; r.v[5] = b.z; r.v[6] = b.w;
    r.v[7] = c.x; r.v[8] = c.y; r.v[9] = c.z;
    return r;
}

__device__ __forceinline__ F7 ld7(const float* __restrict__ P, int r, int c0) {
    float4 a, b, c; ld12(P, r, c0, a, b, c); return mk7(a, b, c);
}
__device__ __forceinline__ F10 ld10(const float* __restrict__ P, int r, int c0) {
    float4 a, b, c; ld12(P, r, c0, a, b, c); return mk10(a, b, c);
}

// ---------------------------------------------------------------------------
// Fat kernel: rows [8, 4087], all cols. Each thread owns cols c0..c0+3 and
// walks RPT rows with rolling register windows; E is computed 7-wide
// (cols c0-1..c0+5) so Hx/Hy need no cross-thread exchange. No LDS, no barrier.
// ---------------------------------------------------------------------------
__global__ __launch_bounds__(BTHREADS, 4) void fat_kernel(
    const float* __restrict__ X1, const float* __restrict__ X2,
    const float* __restrict__ X3, const float* __restrict__ w1,
    float* __restrict__ E, float* __restrict__ Hx, float* __restrict__ Hy)
{
    const int t  = threadIdx.x;
    const int c0 = (blockIdx.x * BTHREADS + t) * 4;
    const int i0 = ROW0 + blockIdx.y * RPT;
    const bool gL = (c0 == 0);
    const bool gR = (c0 == NYg - 4);

    const float wv = w1[0];
    const float f0 = (wv - 1.0f) / 3.0f;
    const float f1 = -wv;
    const float f2 = wv;
    const float f3 = (1.0f - wv) / 3.0f;

    // E row r (7-wide): taps X3[r-2..r+1], X2[r] (10-wide), X1[r] (7-wide).
    // All rows here are in [2,4093] so only column fixups are needed.
    auto eRow = [&](const F7& x3m2, const F7& x3m1, const F7& x3p0, const F7& x3p1,
                    const F10& x2r, const F7& x1r) -> F7 {
        F7 e;
        #pragma unroll
        for (int m = 0; m < 7; ++m) {
            const float e1 = x1r.v[m] + C * (x3p0.v[m] - x3m1.v[m])
                                      - C * (x2r.v[m + 2] - x2r.v[m + 1]);
            e.v[m] = e1
                + C * (f0 * x3m2.v[m] + f1 * x3m1.v[m] + f2 * x3p0.v[m] + f3 * x3p1.v[m])
                - C * (f0 * x2r.v[m] + f1 * x2r.v[m + 1] + f2 * x2r.v[m + 2] + f3 * x2r.v[m + 3]);
        }
        if (gL) {
            // m=1 -> j=0 : boundary copy ; m=2 -> j=1 : BC step only
            e.v[1] = x1r.v[1];
            e.v[2] = x1r.v[2] + C * (x3p0.v[2] - x3m1.v[2])
                              - C * (x2r.v[4] - x2r.v[3]);
        }
        if (gR) {
            // m=4 -> j=4095 : boundary copy ; m=3 -> j=4094 : BC step only
            e.v[4] = x1r.v[4];
            e.v[3] = x1r.v[3] + C * (x3p0.v[3] - x3m1.v[3])
                              - C * (x2r.v[5] - x2r.v[4]);
        }
        return e;
    };

    // ---------------- Prologue: fill windows for i = i0 ----------------
    F7 p3a = ld7(X3, i0 - 3, c0);
    F7 p3b = ld7(X3, i0 - 2, c0);
    F7 p3c = ld7(X3, i0 - 1, c0);
    F7 w3[4];
    w3[0] = ld7(X3, i0,     c0);
    w3[1] = ld7(X3, i0 + 1, c0);
    w3[2] = ld7(X3, i0 + 2, c0);
    w3[3] = ld7(X3, i0 + 3, c0);

    F10 q2a = ld10(X2, i0 - 1, c0);
    F10 q2b = ld10(X2, i0,     c0);
    F10 q2c = ld10(X2, i0 + 1, c0);
    F10 w2r = ld10(X2, i0 + 2, c0);   // X2 row i+2

    F7 q1a = ld7(X1, i0 - 1, c0);
    F7 w1r[3];
    w1r[0] = ld7(X1, i0,     c0);
    w1r[1] = ld7(X1, i0 + 1, c0);
    w1r[2] = ld7(X1, i0 + 2, c0);

    F7 ew[4];                          // E rows i-1 .. i+2
    ew[0] = eRow(p3a, p3b, p3c, w3[0], q2a, q1a);        // E[i0-1]
    ew[1] = eRow(p3b, p3c, w3[0], w3[1], q2b, w1r[0]);   // E[i0]
    ew[2] = eRow(p3c, w3[0], w3[1], w3[2], q2c, w1r[1]); // E[i0+1]

    float x2c0[4] = {q2b.v[3], q2b.v[4], q2b.v[5], q2b.v[6]};  // X2[i] centers
    float x2c1[4] = {q2c.v[3], q2c.v[4], q2c.v[5], q2c.v[6]};  // X2[i+1] centers

    // ---------------- Main loop over output rows ----------------
    #pragma unroll
    for (int s = 0; s < RPT; ++s) {
        const int i = i0 + s;

        // issue next-step loads early (consumed next iteration)
        F7  t3; F10 t2; F7 t1;
        if (s < RPT - 1) {
            t3 = ld7(X3, i + 4, c0);
            t2 = ld10(X2, i + 3, c0);
            t1 = ld7(X1, i + 3, c0);
        }

        // E row i+2 from already-resident windows
        ew[3] = eRow(w3[0], w3[1], w3[2], w3[3], w2r, w1r[2]);

        // ---- outputs for row i ----
        float hx[4], hy[4];
        #pragma unroll
        for (int q = 0; q < 4; ++q) {
            hx[q] = x2c0[q] - C * (w1r[0].v[q + 2] - w1r[0].v[q + 1])
                  - C * (f0 * ew[1].v[q]     + f1 * ew[1].v[q + 1]
                       + f2 * ew[1].v[q + 2] + f3 * ew[1].v[q + 3]);
            hy[q] = w3[0].v[q + 1] + C * (w1r[1].v[q + 1] - w1r[0].v[q + 1])
                  + C * (f0 * ew[0].v[q + 1] + f1 * ew[1].v[q + 1]
                       + f2 * ew[2].v[q + 1] + f3 * ew[3].v[q + 1]);
        }
        if (gL) {
            hx[0] = x2c0[0] - C * (w1r[0].v[2] - w1r[0].v[1]);    // j=0: no f4
            hy[0] = w3[0].v[1];                                   // j=0: copy X3
            hy[1] = w3[0].v[2] + C * (w1r[1].v[2] - w1r[0].v[2]); // j=1: no f4
        }
        if (gR) {
            hx[3] = x2c0[3];                                      // j=4095: copy X2
            hy[3] = w3[0].v[4];                                   // j=4095: copy X3
            hx[2] = x2c0[2] - C * (w1r[0].v[4] - w1r[0].v[3]);    // j=4094: no f4
            hy[2] = w3[0].v[3] + C * (w1r[1].v[3] - w1r[0].v[3]); // j=4094: no f4
        }

        const size_t idx = (size_t)i * NYg + c0;
        *(float4*)(E  + idx) = make_float4(ew[1].v[1], ew[1].v[2], ew[1].v[3], ew[1].v[4]);
        *(float4*)(Hx + idx) = make_float4(hx[0], hx[1], hx[2], hx[3]);
        *(float4*)(Hy + idx) = make_float4(hy[0], hy[1], hy[2], hy[3]);

        // ---- roll windows ----
        ew[0] = ew[1]; ew[1] = ew[2]; ew[2] = ew[3];
        w3[0] = w3[1]; w3[1] = w3[2]; w3[2] = w3[3];
        w1r[0] = w1r[1]; w1r[1] = w1r[2];
        #pragma unroll
        for (int q = 0; q < 4; ++q) { x2c0[q] = x2c1[q]; x2c1[q] = w2r.v[3 + q]; }
        if (s < RPT - 1) { w3[3] = t3; w2r = t2; w1r[2] = t1; }
    }
}

// ---------------------------------------------------------------------------
// Edge kernel: boundary row bands [0,7] and [4088,4095], fully guarded.
// ---------------------------------------------------------------------------
#define TRE 8
#define EROWSE 12
#define ECOLSE 136

__global__ __launch_bounds__(256) void edge_kernel(
    const float* __restrict__ X1, const float* __restrict__ X2,
    const float* __restrict__ X3, const float* __restrict__ w1,
    float* __restrict__ E, float* __restrict__ Hx, float* __restrict__ Hy)
{
    __shared__ float elds[EROWSE][ECOLSE];
    const int t    = threadIdx.x;
    const int row0 = blockIdx.y ? (NXg - TRE) : 0;
    const int col0 = blockIdx.x * 128;

    const float wv = w1[0];
    const float f0 = (wv - 1.0f) / 3.0f;
    const float f1 = -wv;
    const float f2 = wv;
    const float f3 = (1.0f - wv) / 3.0f;

    for (int cidx = t; cidx < EROWSE * ECOLSE; cidx += 256) {
        const int r  = cidx / ECOLSE;
        const int cc = cidx - r * ECOLSE;
        const int gr = row0 - 2 + r;
        const int gc = col0 - 4 + cc;
        float e = 0.0f;
        if (gr >= 0 && gr < NXg && gc >= 0 && gc < NYg) {
            const size_t idx = (size_t)gr * NYg + gc;
            const float x1 = X1[idx];
            if (gr == 0 || gr == NXg - 1 || gc == 0 || gc == NYg - 1) {
                e = x1;
            } else {
                float e1 = x1 + C * (X3[idx] - X3[idx - NYg])
                              - C * (X2[idx] - X2[idx - 1]);
                if (gr >= 2 && gr <= NXg - 3 && gc >= 2 && gc <= NYg - 3) {
                    e1 += C * (f0 * X3[idx - 2 * NYg] + f1 * X3[idx - NYg]
                             + f2 * X3[idx] + f3 * X3[idx + NYg])
                        - C * (f0 * X2[idx - 2] + f1 * X2[idx - 1]
                             + f2 * X2[idx] + f3 * X2[idx + 1]);
                }
                e = e1;
            }
        }
        elds[r][cc] = e;
    }
    __syncthreads();

    for (int cidx = t; cidx < TRE * 128; cidx += 256) {
        const int hr  = cidx >> 7;
        const int tc  = cidx & 127;
        const int gr  = row0 + hr;
        const int gcc = col0 + tc;
        const size_t idx = (size_t)gr * NYg + gcc;
        const int lr  = hr + 2;
        const int lc2 = tc + 4;

        const float ec = elds[lr][lc2];
        E[idx] = ec;

        const float x1 = X1[idx];

        float hx = X2[idx];
        if (gr >= 1 && gr <= NXg - 2 && gcc <= NYg - 2)
            hx -= C * (X1[idx + 1] - x1);
        if (gr >= 2 && gr <= NXg - 3 && gcc >= 1 && gcc <= NYg - 3) {
            hx -= C * (f0 * elds[lr][lc2 - 1] + f1 * ec
                     + f2 * elds[lr][lc2 + 1] + f3 * elds[lr][lc2 + 2]);
        }
        Hx[idx] = hx;

        float hy = X3[idx];
        if (gr <= NXg - 2 && gcc >= 1 && gcc <= NYg - 2)
            hy += C * (X1[idx + NYg] - x1);
        if (gr >= 1 && gr <= NXg - 3 && gcc >= 2 && gcc <= NYg - 3) {
            hy += C * (f0 * elds[lr - 1][lc2] + f1 * ec
                     + f2 * elds[lr + 1][lc2] + f3 * elds[lr + 2][lc2]);
        }
        Hy[idx] = hy;
    }
}

extern "C" void kernel_launch(void* const* d_in, const int* in_sizes, int n_in,
                              void* d_out, int out_size, void* d_ws, size_t ws_size,
                              hipStream_t stream) {
    const float* X1 = (const float*)d_in[0];
    const float* X2 = (const float*)d_in[1];
    const float* X3 = (const float*)d_in[2];
    const float* w1 = (const float*)d_in[3];

    float* E  = (float*)d_out;
    float* Hx = (float*)d_out + (size_t)NXg * NYg;
    float* Hy = (float*)d_out + 2 * (size_t)NXg * NYg;

    edge_kernel<<<dim3(32, 2), 256, 0, stream>>>(X1, X2, X3, w1, E, Hx, Hy);
    fat_kernel <<<dim3(NYg / (BTHREADS * 4), NBANDS), BTHREADS, 0, stream>>>(
        X1, X2, X3, w1, E, Hx, Hy);
}

// Round 6
// 105.396 us; speedup vs baseline: 2.2250x; 1.0600x over previous
//
#include <hip/hip_runtime.h>

#define NXg 4096
#define NYg 4096
#define RPT 8                  // output rows per thread (fat kernel)
#define ROW0 8                 // fat kernel covers rows [8, 4087]
#define NBANDS 510             // (4088-8)/RPT
#define BTHREADS 128           // threads per block (2 waves); block covers 512 cols

static constexpr float C = 10.2375f;   // Z*DT/DX = (1/400)*4095 ; DX==DY

struct F7  { float v[7];  };   // cols c0-1 .. c0+5
struct F10 { float v[10]; };   // cols c0-3 .. c0+6

// Load 12 consecutive floats at row r, cols c0-4 .. c0+7 (three aligned float4).
// In-bounds for all uses: r in [5, 4091] -> o-4 >= 0, o+4+3 < 4096^2.
// At col edges the outer float4s contain neighboring-row data; consumed only by
// lanes whose results are overridden by gL/gR fixups.
__device__ __forceinline__ void ld12(const float* __restrict__ P, int r, int c0,
                                     float4& a, float4& b, float4& c) {
    const size_t o = (size_t)r * NYg + c0;
    a = *(const float4*)(P + o - 4);
    b = *(const float4*)(P + o);
    c = *(const float4*)(P + o + 4);
}

__device__ __forceinline__ F7 mk7(const float4& a, const float4& b, const float4& c) {
    F7 r;
    r.v[0] = a.w; r.v[1] = b.x; r.v[2] = b.y; r.v[3] = b.z;
    r.v[4] = b.w; r.v[5] = c.x; r.v[6] = c.y;
    return r;
}
__device__ __forceinline__ F10 mk10(const float4& a, const float4& b, const float4& c) {
    F10 r;
    r.v[0] = a.y; r.v[1] = a.z; r.v[2] = a.w;
    r.v[3] = b.x; r.v[4] = b.y; r.v[5] = b.z; r.v[6] = b.w;
    r.v[7] = c.x; r.v[8] = c.y; r.v[9] = c.z;
    return r;
}

__device__ __forceinline__ F7 ld7(const float* __restrict__ P, int r, int c0) {
    float4 a, b, c; ld12(P, r, c0, a, b, c); return mk7(a, b, c);
}
__device__ __forceinline__ F10 ld10(const float* __restrict__ P, int r, int c0) {
    float4 a, b, c; ld12(P, r, c0, a, b, c); return mk10(a, b, c);
}

// ---------------------------------------------------------------------------
// Fat kernel: rows [8, 4087], all cols. Each thread owns cols c0..c0+3 and
// walks RPT rows with rolling register windows; E is computed 7-wide
// (cols c0-1..c0+5) so Hx/Hy need no cross-thread exchange. No LDS, no barrier.
// __launch_bounds__(128, 2): VGPR cap 256 — the live windows + 9-float4
// prefetch group need ~150 VGPRs; capping at 128 (r4/r5) collapsed the
// pipeline to serial demand-loads (VGPR=64, per-wave VALU duty ~4%).
// ---------------------------------------------------------------------------
__global__ __launch_bounds__(BTHREADS, 2) void fat_kernel(
    const float* __restrict__ X1, const float* __restrict__ X2,
    const float* __restrict__ X3, const float* __restrict__ w1,
    float* __restrict__ E, float* __restrict__ Hx, float* __restrict__ Hy)
{
    const int t  = threadIdx.x;
    const int c0 = (blockIdx.x * BTHREADS + t) * 4;
    const int i0 = ROW0 + blockIdx.y * RPT;
    const bool gL = (c0 == 0);
    const bool gR = (c0 == NYg - 4);

    const float wv = w1[0];
    const float f0 = (wv - 1.0f) / 3.0f;
    const float f1 = -wv;
    const float f2 = wv;
    const float f3 = (1.0f - wv) / 3.0f;

    // E row r (7-wide): taps X3[r-2..r+1], X2[r] (10-wide), X1[r] (7-wide).
    // All rows here are in [2,4093] so only column fixups are needed.
    auto eRow = [&](const F7& x3m2, const F7& x3m1, const F7& x3p0, const F7& x3p1,
                    const F10& x2r, const F7& x1r) -> F7 {
        F7 e;
        #pragma unroll
        for (int m = 0; m < 7; ++m) {
            const float e1 = x1r.v[m] + C * (x3p0.v[m] - x3m1.v[m])
                                      - C * (x2r.v[m + 2] - x2r.v[m + 1]);
            e.v[m] = e1
                + C * (f0 * x3m2.v[m] + f1 * x3m1.v[m] + f2 * x3p0.v[m] + f3 * x3p1.v[m])
                - C * (f0 * x2r.v[m] + f1 * x2r.v[m + 1] + f2 * x2r.v[m + 2] + f3 * x2r.v[m + 3]);
        }
        if (gL) {
            // m=1 -> j=0 : boundary copy ; m=2 -> j=1 : BC step only
            e.v[1] = x1r.v[1];
            e.v[2] = x1r.v[2] + C * (x3p0.v[2] - x3m1.v[2])
                              - C * (x2r.v[4] - x2r.v[3]);
        }
        if (gR) {
            // m=4 -> j=4095 : boundary copy ; m=3 -> j=4094 : BC step only
            e.v[4] = x1r.v[4];
            e.v[3] = x1r.v[3] + C * (x3p0.v[3] - x3m1.v[3])
                              - C * (x2r.v[5] - x2r.v[4]);
        }
        return e;
    };

    // ---------------- Prologue: fill windows for i = i0 ----------------
    F7 p3a = ld7(X3, i0 - 3, c0);
    F7 p3b = ld7(X3, i0 - 2, c0);
    F7 p3c = ld7(X3, i0 - 1, c0);
    F7 w3[4];
    w3[0] = ld7(X3, i0,     c0);
    w3[1] = ld7(X3, i0 + 1, c0);
    w3[2] = ld7(X3, i0 + 2, c0);
    w3[3] = ld7(X3, i0 + 3, c0);

    F10 q2a = ld10(X2, i0 - 1, c0);
    F10 q2b = ld10(X2, i0,     c0);
    F10 q2c = ld10(X2, i0 + 1, c0);
    F10 w2r = ld10(X2, i0 + 2, c0);   // X2 row i+2

    F7 q1a = ld7(X1, i0 - 1, c0);
    F7 w1r[3];
    w1r[0] = ld7(X1, i0,     c0);
    w1r[1] = ld7(X1, i0 + 1, c0);
    w1r[2] = ld7(X1, i0 + 2, c0);

    F7 ew[4];                          // E rows i-1 .. i+2
    ew[0] = eRow(p3a, p3b, p3c, w3[0], q2a, q1a);        // E[i0-1]
    ew[1] = eRow(p3b, p3c, w3[0], w3[1], q2b, w1r[0]);   // E[i0]
    ew[2] = eRow(p3c, w3[0], w3[1], w3[2], q2c, w1r[1]); // E[i0+1]

    float x2c0[4] = {q2b.v[3], q2b.v[4], q2b.v[5], q2b.v[6]};  // X2[i] centers
    float x2c1[4] = {q2c.v[3], q2c.v[4], q2c.v[5], q2c.v[6]};  // X2[i+1] centers

    // ---------------- Main loop over output rows ----------------
    #pragma unroll
    for (int s = 0; s < RPT; ++s) {
        const int i = i0 + s;

        // issue next-step loads early (consumed next iteration)
        F7  t3; F10 t2; F7 t1;
        if (s < RPT - 1) {
            t3 = ld7(X3, i + 4, c0);
            t2 = ld10(X2, i + 3, c0);
            t1 = ld7(X1, i + 3, c0);
        }

        // E row i+2 from already-resident windows
        ew[3] = eRow(w3[0], w3[1], w3[2], w3[3], w2r, w1r[2]);

        // ---- outputs for row i ----
        float hx[4], hy[4];
        #pragma unroll
        for (int q = 0; q < 4; ++q) {
            hx[q] = x2c0[q] - C * (w1r[0].v[q + 2] - w1r[0].v[q + 1])
                  - C * (f0 * ew[1].v[q]     + f1 * ew[1].v[q + 1]
                       + f2 * ew[1].v[q + 2] + f3 * ew[1].v[q + 3]);
            hy[q] = w3[0].v[q + 1] + C * (w1r[1].v[q + 1] - w1r[0].v[q + 1])
                  + C * (f0 * ew[0].v[q + 1] + f1 * ew[1].v[q + 1]
                       + f2 * ew[2].v[q + 1] + f3 * ew[3].v[q + 1]);
        }
        if (gL) {
            hx[0] = x2c0[0] - C * (w1r[0].v[2] - w1r[0].v[1]);    // j=0: no f4
            hy[0] = w3[0].v[1];                                   // j=0: copy X3
            hy[1] = w3[0].v[2] + C * (w1r[1].v[2] - w1r[0].v[2]); // j=1: no f4
        }
        if (gR) {
            hx[3] = x2c0[3];                                      // j=4095: copy X2
            hy[3] = w3[0].v[4];                                   // j=4095: copy X3
            hx[2] = x2c0[2] - C * (w1r[0].v[4] - w1r[0].v[3]);    // j=4094: no f4
            hy[2] = w3[0].v[3] + C * (w1r[1].v[3] - w1r[0].v[3]); // j=4094: no f4
        }

        const size_t idx = (size_t)i * NYg + c0;
        *(float4*)(E  + idx) = make_float4(ew[1].v[1], ew[1].v[2], ew[1].v[3], ew[1].v[4]);
        *(float4*)(Hx + idx) = make_float4(hx[0], hx[1], hx[2], hx[3]);
        *(float4*)(Hy + idx) = make_float4(hy[0], hy[1], hy[2], hy[3]);

        // ---- roll windows ----
        ew[0] = ew[1]; ew[1] = ew[2]; ew[2] = ew[3];
        w3[0] = w3[1]; w3[1] = w3[2]; w3[2] = w3[3];
        w1r[0] = w1r[1]; w1r[1] = w1r[2];
        #pragma unroll
        for (int q = 0; q < 4; ++q) { x2c0[q] = x2c1[q]; x2c1[q] = w2r.v[3 + q]; }
        if (s < RPT - 1) { w3[3] = t3; w2r = t2; w1r[2] = t1; }
    }
}

// ---------------------------------------------------------------------------
// Edge kernel: boundary row bands [0,7] and [4088,4095], fully guarded.
// ---------------------------------------------------------------------------
#define TRE 8
#define EROWSE 12
#define ECOLSE 136

__global__ __launch_bounds__(256) void edge_kernel(
    const float* __restrict__ X1, const float* __restrict__ X2,
    const float* __restrict__ X3, const float* __restrict__ w1,
    float* __restrict__ E, float* __restrict__ Hx, float* __restrict__ Hy)
{
    __shared__ float elds[EROWSE][ECOLSE];
    const int t    = threadIdx.x;
    const int row0 = blockIdx.y ? (NXg - TRE) : 0;
    const int col0 = blockIdx.x * 128;

    const float wv = w1[0];
    const float f0 = (wv - 1.0f) / 3.0f;
    const float f1 = -wv;
    const float f2 = wv;
    const float f3 = (1.0f - wv) / 3.0f;

    for (int cidx = t; cidx < EROWSE * ECOLSE; cidx += 256) {
        const int r  = cidx / ECOLSE;
        const int cc = cidx - r * ECOLSE;
        const int gr = row0 - 2 + r;
        const int gc = col0 - 4 + cc;
        float e = 0.0f;
        if (gr >= 0 && gr < NXg && gc >= 0 && gc < NYg) {
            const size_t idx = (size_t)gr * NYg + gc;
            const float x1 = X1[idx];
            if (gr == 0 || gr == NXg - 1 || gc == 0 || gc == NYg - 1) {
                e = x1;
            } else {
                float e1 = x1 + C * (X3[idx] - X3[idx - NYg])
                              - C * (X2[idx] - X2[idx - 1]);
                if (gr >= 2 && gr <= NXg - 3 && gc >= 2 && gc <= NYg - 3) {
                    e1 += C * (f0 * X3[idx - 2 * NYg] + f1 * X3[idx - NYg]
                             + f2 * X3[idx] + f3 * X3[idx + NYg])
                        - C * (f0 * X2[idx - 2] + f1 * X2[idx - 1]
                             + f2 * X2[idx] + f3 * X2[idx + 1]);
                }
                e = e1;
            }
        }
        elds[r][cc] = e;
    }
    __syncthreads();

    for (int cidx = t; cidx < TRE * 128; cidx += 256) {
        const int hr  = cidx >> 7;
        const int tc  = cidx & 127;
        const int gr  = row0 + hr;
        const int gcc = col0 + tc;
        const size_t idx = (size_t)gr * NYg + gcc;
        const int lr  = hr + 2;
        const int lc2 = tc + 4;

        const float ec = elds[lr][lc2];
        E[idx] = ec;

        const float x1 = X1[idx];

        float hx = X2[idx];
        if (gr >= 1 && gr <= NXg - 2 && gcc <= NYg - 2)
            hx -= C * (X1[idx + 1] - x1);
        if (gr >= 2 && gr <= NXg - 3 && gcc >= 1 && gcc <= NYg - 3) {
            hx -= C * (f0 * elds[lr][lc2 - 1] + f1 * ec
                     + f2 * elds[lr][lc2 + 1] + f3 * elds[lr][lc2 + 2]);
        }
        Hx[idx] = hx;

        float hy = X3[idx];
        if (gr <= NXg - 2 && gcc >= 1 && gcc <= NYg - 2)
            hy += C * (X1[idx + NYg] - x1);
        if (gr >= 1 && gr <= NXg - 3 && gcc >= 2 && gcc <= NYg - 3) {
            hy += C * (f0 * elds[lr - 1][lc2] + f1 * ec
                     + f2 * elds[lr + 1][lc2] + f3 * elds[lr + 2][lc2]);
        }
        Hy[idx] = hy;
    }
}

extern "C" void kernel_launch(void* const* d_in, const int* in_sizes, int n_in,
                              void* d_out, int out_size, void* d_ws, size_t ws_size,
                              hipStream_t stream) {
    const float* X1 = (const float*)d_in[0];
    const float* X2 = (const float*)d_in[1];
    const float* X3 = (const float*)d_in[2];
    const float* w1 = (const float*)d_in[3];

    float* E  = (float*)d_out;
    float* Hx = (float*)d_out + (size_t)NXg * NYg;
    float* Hy = (float*)d_out + 2 * (size_t)NXg * NYg;

    edge_kernel<<<dim3(32, 2), 256, 0, stream>>>(X1, X2, X3, w1, E, Hx, Hy);
    fat_kernel <<<dim3(NYg / (BTHREADS * 4), NBANDS), BTHREADS, 0, stream>>>(
        X1, X2, X3, w1, E, Hx, Hy);
}